// Round 5
// baseline (184.799 us; speedup 1.0000x reference)
//
#include <hip/hip_runtime.h>

#define T_SEQ 4096
#define NBATCH 4
#define EMB 1024
#define HS 64
#define BT (NBATCH * T_SEQ)   // 16384 token rows

typedef float f32x4 __attribute__((ext_vector_type(4)));
typedef short s16x8 __attribute__((ext_vector_type(8)));

__device__ __forceinline__ unsigned short f2bf(float x) {  // RNE fp32->bf16
  union { float f; unsigned u; } c; c.f = x;
  unsigned r = c.u + 0x7FFF + ((c.u >> 16) & 1);
  return (unsigned short)(r >> 16);
}
__device__ __forceinline__ float bf2f(unsigned short h) {
  union { unsigned u; float f; } c; c.u = ((unsigned)h) << 16;
  return c.f;
}
// RNE hi/lo split (cold paths: wconv, epilogues, attn Q)
__device__ __forceinline__ void cvt8(float4 a0, float4 a1, s16x8& hi, s16x8& lo) {
  float xv[8] = {a0.x, a0.y, a0.z, a0.w, a1.x, a1.y, a1.z, a1.w};
#pragma unroll
  for (int j = 0; j < 8; ++j) {
    unsigned short h = f2bf(xv[j]);
    hi[j] = (short)h;
    lo[j] = (short)f2bf(xv[j] - bf2f(h));
  }
}
// TRUNCATION hi/lo split for the qkv hot loop (R4-proven: VALUBusy 21->15,
// absmax unchanged). hi = top16(x), lo = top16(x - hi).
__device__ __forceinline__ void cvt8t(float4 a0, float4 a1, s16x8& hi, s16x8& lo) {
  float xv[8] = {a0.x, a0.y, a0.z, a0.w, a1.x, a1.y, a1.z, a1.w};
  unsigned hu[8], lu[8];
#pragma unroll
  for (int j = 0; j < 8; ++j) {
    union { float f; unsigned u; } c; c.f = xv[j];
    hu[j] = c.u;
    union { unsigned u; float f; } hf; hf.u = c.u & 0xFFFF0000u;
    union { float f; unsigned u; } r; r.f = xv[j] - hf.f;
    lu[j] = r.u;
  }
  union { s16x8 v; unsigned u[4]; } H, L;
#pragma unroll
  for (int j = 0; j < 4; ++j) {
    H.u[j] = (hu[2 * j] >> 16) | (hu[2 * j + 1] & 0xFFFF0000u);
    L.u[j] = (lu[2 * j] >> 16) | (lu[2 * j + 1] & 0xFFFF0000u);
  }
  hi = H.v; lo = L.v;
}

// ---------------- Kernel 0: W -> W^T hi/lo bf16 (verbatim) ---------------
__global__ __launch_bounds__(256) void wconv(
    const float* __restrict__ Wq, const float* __restrict__ Wk,
    const float* __restrict__ Wv, unsigned short* __restrict__ wt_hi,
    unsigned short* __restrict__ wt_lo) {
  const int n3 = blockIdx.x;
  const int which = n3 >> 6, n = n3 & 63;
  const float* W = (which == 0) ? Wq : (which == 1) ? Wk : Wv;
#pragma unroll
  for (int i = 0; i < 4; ++i) {
    int k = i * 256 + threadIdx.x;
    float x = W[(size_t)k * HS + n];
    unsigned short h = f2bf(x);
    wt_hi[(size_t)n3 * EMB + k] = h;
    wt_lo[(size_t)n3 * EMB + k] = f2bf(x - bf2f(h));
  }
}

// ---------------- Kernel 1: QKV projection v6 ----------------------------
// The (a)+(b) combination the round history demands:
//   (a) 36 MFMA/wave per barrier interval (R1/R4 density)
//   (b) 2 INDEPENDENT blocks/CU (R3's overlap, m114)
// 64 tok x 96-col half-panel per block, grid 512, K-chunk 128 (8 iters),
// single-buffered LDS 52.2KB/block -> 104KB/CU for two blocks. 8 waves =
// 4 row-groups x 2 col-groups; wave = 16 rows x 48 cols.
// NATURAL register allocation (R2 ERRATA: launch_bounds(512,4) forced
// VGPR=64 -> 225MB scratch spill; live set is ~115, needs <=128 for
// 4 waves/SIMD). cvt8t from R4.
__global__ __launch_bounds__(512) void qkv_mfma(
    const float* __restrict__ inp, const unsigned short* __restrict__ wt_hi,
    const unsigned short* __restrict__ wt_lo, float* __restrict__ qf,
    unsigned short* __restrict__ khi, unsigned short* __restrict__ klo,
    unsigned short* __restrict__ vtb) {
  __shared__ unsigned short Bhi[96 * 136];
  __shared__ unsigned short Blo[96 * 136];
  const int t = threadIdx.x, lane = t & 63, w = t >> 6;
  const int m = lane & 15, quad = lane >> 4;
  const int mg = w >> 1, ng = w & 1;
  const int rc = blockIdx.x >> 1;     // 64-token row chunk
  const int half = blockIdx.x & 1;    // which 96-col half of the 192 panel
  const int tok0 = rc * 64;
  const int arow = tok0 + mg * 16 + m;
  const int colbase = half * 96;

  f32x4 acc[3];
#pragma unroll
  for (int nt = 0; nt < 3; ++nt) acc[nt] = (f32x4){0.f, 0.f, 0.f, 0.f};

  // staging: 96 rows x 128 K shorts = 1536 uint4 slots per array.
  // thread t owns slots t, t+512, t+1024.  slot s: n3 = s>>4, k8 = s&15.
  const int s0 = t, s1 = t + 512, s2 = t + 1024;
  const int n3_0 = s0 >> 4, k8_0 = s0 & 15;
  const int n3_1 = s1 >> 4, k8_1 = s1 & 15;
  const int n3_2 = s2 >> 4, k8_2 = s2 & 15;
  const size_t goff0 = (size_t)(colbase + n3_0) * EMB + k8_0 * 8;
  const size_t goff1 = (size_t)(colbase + n3_1) * EMB + k8_1 * 8;
  const size_t goff2 = (size_t)(colbase + n3_2) * EMB + k8_2 * 8;
  const int lds0 = n3_0 * 136 + k8_0 * 8;
  const int lds1 = n3_1 * 136 + k8_1 * 8;
  const int lds2 = n3_2 * 136 + k8_2 * 8;

  uint4 ph0, ph1, ph2, pl0, pl1, pl2;
  float4 pa0, pa1, pa2, pa3, pa4, pa5, pa6, pa7;
  ph0 = *(const uint4*)&wt_hi[goff0];
  ph1 = *(const uint4*)&wt_hi[goff1];
  ph2 = *(const uint4*)&wt_hi[goff2];
  pl0 = *(const uint4*)&wt_lo[goff0];
  pl1 = *(const uint4*)&wt_lo[goff1];
  pl2 = *(const uint4*)&wt_lo[goff2];
  {
    const float* ap = &inp[(size_t)arow * EMB + quad * 8];
    pa0 = *(const float4*)ap;        pa1 = *(const float4*)(ap + 4);
    pa2 = *(const float4*)(ap + 32); pa3 = *(const float4*)(ap + 36);
    pa4 = *(const float4*)(ap + 64); pa5 = *(const float4*)(ap + 68);
    pa6 = *(const float4*)(ap + 96); pa7 = *(const float4*)(ap + 100);
  }

#pragma unroll 1
  for (int kc = 0; kc < 8; ++kc) {
    __syncthreads();  // previous iteration's B readers done
    *(uint4*)&Bhi[lds0] = ph0;
    *(uint4*)&Bhi[lds1] = ph1;
    *(uint4*)&Bhi[lds2] = ph2;
    *(uint4*)&Blo[lds0] = pl0;
    *(uint4*)&Blo[lds1] = pl1;
    *(uint4*)&Blo[lds2] = pl2;
    __syncthreads();

    s16x8 ah0, al0, ah1, al1, ah2, al2, ah3, al3;
    cvt8t(pa0, pa1, ah0, al0);
    cvt8t(pa2, pa3, ah1, al1);
    cvt8t(pa4, pa5, ah2, al2);
    cvt8t(pa6, pa7, ah3, al3);

    if (kc < 7) {  // 1-iter lookahead covered by the 36-MFMA phase
      const int k0n = (kc + 1) * 128;
      ph0 = *(const uint4*)&wt_hi[goff0 + k0n];
      ph1 = *(const uint4*)&wt_hi[goff1 + k0n];
      ph2 = *(const uint4*)&wt_hi[goff2 + k0n];
      pl0 = *(const uint4*)&wt_lo[goff0 + k0n];
      pl1 = *(const uint4*)&wt_lo[goff1 + k0n];
      pl2 = *(const uint4*)&wt_lo[goff2 + k0n];
      const float* ap = &inp[(size_t)arow * EMB + k0n + quad * 8];
      pa0 = *(const float4*)ap;        pa1 = *(const float4*)(ap + 4);
      pa2 = *(const float4*)(ap + 32); pa3 = *(const float4*)(ap + 36);
      pa4 = *(const float4*)(ap + 64); pa5 = *(const float4*)(ap + 68);
      pa6 = *(const float4*)(ap + 96); pa7 = *(const float4*)(ap + 100);
    }

#define MFMA3(AH, AL, CCOFF, A)                                              \
    {                                                                        \
      s16x8 bh = *(const s16x8*)&Bhi[bbase + (CCOFF) + quad * 8];            \
      s16x8 bl = *(const s16x8*)&Blo[bbase + (CCOFF) + quad * 8];            \
      A = __builtin_amdgcn_mfma_f32_16x16x32_bf16(AH, bh, A, 0, 0, 0);       \
      A = __builtin_amdgcn_mfma_f32_16x16x32_bf16(AH, bl, A, 0, 0, 0);       \
      A = __builtin_amdgcn_mfma_f32_16x16x32_bf16(AL, bh, A, 0, 0, 0);       \
    }

#pragma unroll
    for (int nt = 0; nt < 3; ++nt) {
      const int bbase = (ng * 48 + nt * 16 + m) * 136;
      f32x4 a = acc[nt];
      MFMA3(ah0, al0, 0, a);
      MFMA3(ah1, al1, 32, a);
      MFMA3(ah2, al2, 64, a);
      MFMA3(ah3, al3, 96, a);
      acc[nt] = a;
    }
#undef MFMA3
  }

  // epilogue: C row = quad*4+r (token), col = m
#pragma unroll
  for (int nt = 0; nt < 3; ++nt) {
    int n3 = colbase + ng * 48 + nt * 16 + m;
    int which = n3 >> 6, col = n3 & 63;
#pragma unroll
    for (int r = 0; r < 4; ++r) {
      int tok = tok0 + mg * 16 + quad * 4 + r;
      float val = acc[nt][r];
      if (which == 0) {
        qf[(size_t)tok * HS + col] = val;
      } else if (which == 1) {
        unsigned short h = f2bf(val);
        khi[(size_t)tok * HS + col] = h;
        klo[(size_t)tok * HS + col] = f2bf(val - bf2f(h));
      } else {
        vtb[(size_t)(tok >> 6) * 4096 + (size_t)col * 64 + (tok & 63)] = f2bf(val);
      }
    }
  }
}

// ---------------- Kernel 2a: flash partials (verbatim — best measured) ----
__global__ __launch_bounds__(256) void attn_part(
    const float* __restrict__ q, const unsigned short* __restrict__ khi,
    const unsigned short* __restrict__ klo, const unsigned short* __restrict__ vt,
    unsigned short* __restrict__ partO, float* __restrict__ partML) {
  __shared__ unsigned short Khi_s[64 * 72];
  __shared__ unsigned short Klo_s[64 * 72];
  __shared__ unsigned short Vt_s[64 * 72];
  __shared__ unsigned short P_s[4 * 16 * 72];
  const int t = threadIdx.x;
  const int lane = t & 63, w = t >> 6;
  const int m = lane & 15, quad = lane >> 4;

  int u = blockIdx.x;
  const int b = u / 160;
  u -= b * 160;
  int qtile = 0, c = 0;
  {
    int acc2 = 0;
    for (int qq = 0; qq < 64; ++qq) {
      int ncq = (qq >> 4) + 1;
      if (u < acc2 + ncq) { qtile = qq; c = u - acc2; break; }
      acc2 += ncq;
    }
  }
  const int kt0 = c * 16;
  const int kt1 = (kt0 + 16 < qtile + 1) ? kt0 + 16 : qtile + 1;

  const size_t qrow0 = (size_t)b * T_SEQ + (size_t)qtile * 64;
  const size_t krowbase = (size_t)b * T_SEQ;
  const int q_loc = w * 16 + m;

  s16x8 qh[2], ql[2];
#pragma unroll
  for (int cc = 0; cc < 2; ++cc) {
    const float* qp = &q[(qrow0 + q_loc) * HS + cc * 32 + quad * 8];
    cvt8(*(const float4*)qp, *(const float4*)(qp + 4), qh[cc], ql[cc]);
  }

  float l_st = 0.f;
  f32x4 o[4];
#pragma unroll
  for (int hb = 0; hb < 4; ++hb) o[hb] = (f32x4){0.f, 0.f, 0.f, 0.f};

  const int r0 = t >> 3, ch0 = t & 7;
  const int r1 = (256 + t) >> 3, ch1 = t & 7;

  uint4 pk0h, pk0l, pv0, pk1h, pk1l, pv1;
  {
    size_t g0 = (krowbase + (size_t)kt0 * 64 + r0) * HS + ch0 * 8;
    size_t g1 = (krowbase + (size_t)kt0 * 64 + r1) * HS + ch1 * 8;
    pk0h = *(const uint4*)&khi[g0]; pk0l = *(const uint4*)&klo[g0];
    pk1h = *(const uint4*)&khi[g1]; pk1l = *(const uint4*)&klo[g1];
    size_t v0 = (size_t)(b * 64 + kt0) * 4096 + (size_t)r0 * 64 + ch0 * 8;
    size_t v1 = (size_t)(b * 64 + kt0) * 4096 + (size_t)r1 * 64 + ch1 * 8;
    pv0 = *(const uint4*)&vt[v0]; pv1 = *(const uint4*)&vt[v1];
  }

  for (int kt = kt0; kt < kt1; ++kt) {
    __syncthreads();
    *(uint4*)&Khi_s[r0 * 72 + ch0 * 8] = pk0h;
    *(uint4*)&Klo_s[r0 * 72 + ch0 * 8] = pk0l;
    *(uint4*)&Vt_s[r0 * 72 + ch0 * 8] = pv0;
    *(uint4*)&Khi_s[r1 * 72 + ch1 * 8] = pk1h;
    *(uint4*)&Klo_s[r1 * 72 + ch1 * 8] = pk1l;
    *(uint4*)&Vt_s[r1 * 72 + ch1 * 8] = pv1;
    __syncthreads();

    if (kt + 1 < kt1) {
      size_t g0 = (krowbase + (size_t)(kt + 1) * 64 + r0) * HS + ch0 * 8;
      size_t g1 = (krowbase + (size_t)(kt + 1) * 64 + r1) * HS + ch1 * 8;
      pk0h = *(const uint4*)&khi[g0]; pk0l = *(const uint4*)&klo[g0];
      pk1h = *(const uint4*)&khi[g1]; pk1l = *(const uint4*)&klo[g1];
      size_t v0 = (size_t)(b * 64 + kt + 1) * 4096 + (size_t)r0 * 64 + ch0 * 8;
      size_t v1 = (size_t)(b * 64 + kt + 1) * 4096 + (size_t)r1 * 64 + ch1 * 8;
      pv0 = *(const uint4*)&vt[v0]; pv1 = *(const uint4*)&vt[v1];
    }

    f32x4 st[4];
#pragma unroll
    for (int cb = 0; cb < 4; ++cb) {
      st[cb] = (f32x4){0.f, 0.f, 0.f, 0.f};
#pragma unroll
      for (int cc = 0; cc < 2; ++cc) {
        s16x8 bh = *(const s16x8*)&Khi_s[(cb * 16 + m) * 72 + cc * 32 + quad * 8];
        s16x8 bl = *(const s16x8*)&Klo_s[(cb * 16 + m) * 72 + cc * 32 + quad * 8];
        st[cb] = __builtin_amdgcn_mfma_f32_16x16x32_bf16(bh, qh[cc], st[cb], 0, 0, 0);
        st[cb] = __builtin_amdgcn_mfma_f32_16x16x32_bf16(bl, qh[cc], st[cb], 0, 0, 0);
        st[cb] = __builtin_amdgcn_mfma_f32_16x16x32_bf16(bh, ql[cc], st[cb], 0, 0, 0);
      }
    }
    if (kt == qtile) {
#pragma unroll
      for (int cb = 0; cb < 4; ++cb)
#pragma unroll
        for (int r = 0; r < 4; ++r)
          if (cb * 16 + quad * 4 + r > q_loc) st[cb][r] = -1e30f;
    }
#pragma unroll
    for (int cb = 0; cb < 4; ++cb)
#pragma unroll
      for (int r = 0; r < 4; ++r) {
        st[cb][r] = __expf(st[cb][r]);
        l_st += st[cb][r];
      }
#pragma unroll
    for (int cb = 0; cb < 4; ++cb) {
      uint2 pk;
      pk.x = (unsigned)f2bf(st[cb][0]) | ((unsigned)f2bf(st[cb][1]) << 16);
      pk.y = (unsigned)f2bf(st[cb][2]) | ((unsigned)f2bf(st[cb][3]) << 16);
      *(uint2*)&P_s[q_loc * 72 + cb * 16 + quad * 4] = pk;
    }
    s16x8 pf[2];
#pragma unroll
    for (int cc = 0; cc < 2; ++cc)
      pf[cc] = *(const s16x8*)&P_s[q_loc * 72 + cc * 32 + quad * 8];
#pragma unroll
    for (int hb = 0; hb < 4; ++hb) {
#pragma unroll
      for (int cc = 0; cc < 2; ++cc) {
        s16x8 vf = *(const s16x8*)&Vt_s[(hb * 16 + m) * 72 + cc * 32 + quad * 8];
        o[hb] = __builtin_amdgcn_mfma_f32_16x16x32_bf16(vf, pf[cc], o[hb], 0, 0, 0);
      }
    }
  }

  l_st += __shfl_xor(l_st, 16, 64);
  l_st += __shfl_xor(l_st, 32, 64);

  const int slot = ((b * 64 + qtile) << 2) + c;
  unsigned short* Op = partO + (size_t)slot * 4096;
#pragma unroll
  for (int hb = 0; hb < 4; ++hb) {
    uint2 pk;
    pk.x = (unsigned)f2bf(o[hb][0]) | ((unsigned)f2bf(o[hb][1]) << 16);
    pk.y = (unsigned)f2bf(o[hb][2]) | ((unsigned)f2bf(o[hb][3]) << 16);
    *(uint2*)&Op[q_loc * 64 + hb * 16 + quad * 4] = pk;
  }
  if (quad == 0) partML[(size_t)slot * 64 + q_loc] = l_st;
}

// ---------------- Kernel 2b: combine = plain sums (flat softmax) ----------
__global__ __launch_bounds__(256) void attn_combine(
    const unsigned short* __restrict__ partO, const float* __restrict__ partML,
    float* __restrict__ out) {
  const int qtile = blockIdx.x, b = blockIdx.y;
  const int t = threadIdx.x;
  const int row = t >> 2, hg = t & 3;
  const int nc = (qtile >> 4) + 1;
  const int slot0 = (b * 64 + qtile) << 2;

  float lsum = 0.f;
  for (int i = 0; i < nc; ++i) lsum += partML[(size_t)(slot0 + i) * 64 + row];
  const float inv = 1.f / (lsum * 8.0f);  // ref divides by sqrt(64) after softmax

  float acc[16];
#pragma unroll
  for (int e = 0; e < 16; ++e) acc[e] = 0.f;
  for (int i = 0; i < nc; ++i) {
    const unsigned short* Op =
        partO + (size_t)(slot0 + i) * 4096 + row * 64 + hg * 16;
    uint4 u0 = *(const uint4*)Op;
    uint4 u1 = *(const uint4*)(Op + 8);
    unsigned uv[8] = {u0.x, u0.y, u0.z, u0.w, u1.x, u1.y, u1.z, u1.w};
#pragma unroll
    for (int e = 0; e < 8; ++e) {
      acc[2 * e] += bf2f((unsigned short)(uv[e] & 0xFFFF));
      acc[2 * e + 1] += bf2f((unsigned short)(uv[e] >> 16));
    }
  }
  float* op = &out[((size_t)b * T_SEQ + (size_t)qtile * 64 + row) * HS + hg * 16];
#pragma unroll
  for (int v = 0; v < 4; ++v) {
    float4 r;
    r.x = acc[4 * v + 0] * inv; r.y = acc[4 * v + 1] * inv;
    r.z = acc[4 * v + 2] * inv; r.w = acc[4 * v + 3] * inv;
    ((float4*)op)[v] = r;
  }
}

extern "C" void kernel_launch(void* const* d_in, const int* in_sizes, int n_in,
                              void* d_out, int out_size, void* d_ws, size_t ws_size,
                              hipStream_t stream) {
  const float* inp = (const float*)d_in[0];
  const float* Wq  = (const float*)d_in[1];
  const float* Wk  = (const float*)d_in[2];
  const float* Wv  = (const float*)d_in[3];
  float* out = (float*)d_out;

  // ws: qf 4MB | khi 2MB | klo 2MB | vt 2MB | wt_hi .375MB | wt_lo .375MB
  //     | partO bf16 8MB | partML 256KB  (~19 MB)
  char* base = (char*)d_ws;
  float* qf = (float*)base;
  unsigned short* khi = (unsigned short*)(base + (size_t)BT * HS * 4);
  unsigned short* klo = khi + (size_t)BT * HS;
  unsigned short* vtb = klo + (size_t)BT * HS;
  unsigned short* wt_hi = vtb + (size_t)BT * HS;
  unsigned short* wt_lo = wt_hi + (size_t)192 * EMB;
  unsigned short* partO = wt_lo + (size_t)192 * EMB;
  float* partML = (float*)(partO + (size_t)1024 * 4096);

  wconv<<<dim3(192), dim3(256), 0, stream>>>(Wq, Wk, Wv, wt_hi, wt_lo);
  qkv_mfma<<<dim3(BT / 64 * 2), dim3(512), 0, stream>>>(inp, wt_hi, wt_lo, qf, khi, klo, vtb);
  attn_part<<<dim3(640), dim3(256), 0, stream>>>(qf, khi, klo, vtb, partO, partML);
  attn_combine<<<dim3(64, NBATCH), dim3(256), 0, stream>>>(partO, partML, out);
}

// Round 6
// 178.080 us; speedup vs baseline: 1.0377x; 1.0377x over previous
//
#include <hip/hip_runtime.h>

#define T_SEQ 4096
#define NBATCH 4
#define EMB 1024
#define HS 64
#define BT (NBATCH * T_SEQ)   // 16384 token rows

typedef float f32x4 __attribute__((ext_vector_type(4)));
typedef short s16x8 __attribute__((ext_vector_type(8)));

__device__ __forceinline__ unsigned short f2bf(float x) {  // RNE fp32->bf16
  union { float f; unsigned u; } c; c.f = x;
  unsigned r = c.u + 0x7FFF + ((c.u >> 16) & 1);
  return (unsigned short)(r >> 16);
}
__device__ __forceinline__ float bf2f(unsigned short h) {
  union { unsigned u; float f; } c; c.u = ((unsigned)h) << 16;
  return c.f;
}
// RNE hi/lo split (cold paths: wconv, epilogues, attn Q)
__device__ __forceinline__ void cvt8(float4 a0, float4 a1, s16x8& hi, s16x8& lo) {
  float xv[8] = {a0.x, a0.y, a0.z, a0.w, a1.x, a1.y, a1.z, a1.w};
#pragma unroll
  for (int j = 0; j < 8; ++j) {
    unsigned short h = f2bf(xv[j]);
    hi[j] = (short)h;
    lo[j] = (short)f2bf(xv[j] - bf2f(h));
  }
}
// TRUNCATION hi/lo split for the qkv hot loop (R4-proven: VALUBusy 21->15,
// absmax unchanged). hi = top16(x), lo = top16(x - hi).
__device__ __forceinline__ void cvt8t(float4 a0, float4 a1, s16x8& hi, s16x8& lo) {
  float xv[8] = {a0.x, a0.y, a0.z, a0.w, a1.x, a1.y, a1.z, a1.w};
  unsigned hu[8], lu[8];
#pragma unroll
  for (int j = 0; j < 8; ++j) {
    union { float f; unsigned u; } c; c.f = xv[j];
    hu[j] = c.u;
    union { unsigned u; float f; } hf; hf.u = c.u & 0xFFFF0000u;
    union { float f; unsigned u; } r; r.f = xv[j] - hf.f;
    lu[j] = r.u;
  }
  union { s16x8 v; unsigned u[4]; } H, L;
#pragma unroll
  for (int j = 0; j < 4; ++j) {
    H.u[j] = (hu[2 * j] >> 16) | (hu[2 * j + 1] & 0xFFFF0000u);
    L.u[j] = (lu[2 * j] >> 16) | (lu[2 * j + 1] & 0xFFFF0000u);
  }
  hi = H.v; lo = L.v;
}

// ---------------- Kernel 0: W -> W^T hi/lo bf16 (verbatim) ---------------
__global__ __launch_bounds__(256) void wconv(
    const float* __restrict__ Wq, const float* __restrict__ Wk,
    const float* __restrict__ Wv, unsigned short* __restrict__ wt_hi,
    unsigned short* __restrict__ wt_lo) {
  const int n3 = blockIdx.x;
  const int which = n3 >> 6, n = n3 & 63;
  const float* W = (which == 0) ? Wq : (which == 1) ? Wk : Wv;
#pragma unroll
  for (int i = 0; i < 4; ++i) {
    int k = i * 256 + threadIdx.x;
    float x = W[(size_t)k * HS + n];
    unsigned short h = f2bf(x);
    wt_hi[(size_t)n3 * EMB + k] = h;
    wt_lo[(size_t)n3 * EMB + k] = f2bf(x - bf2f(h));
  }
}

// ---------------- Kernel 1: QKV projection v7 ----------------------------
// R4 base (45us: 64tok x 192col, K-chunk 64, dbuf LDS, ONE barrier/subtile,
// grid 256, cvt8t) with the wave decomposition changed:
//   OLD 4rg x 2cg: wave = 16 rows x 96 cols -> 24 B-reads per 36 MFMA
//   NEW 2rg x 4cg: wave = 32 rows x 48 cols -> 12 B-reads per 36 MFMA
// Counter evidence (R4/R5): LDS read pipe is the dominant per-subtile cost
// (192 ds_read_b128/subtile ~2500cyc vs 350cyc MFMA); the 2 row-frags
// share every B fragment in-register, halving block-level LDS read
// traffic. Cost: A converted by 4 col-waves (cvt x2) and A-prefetch regs
// x2 — natural allocation (VGPR est ~150-190; spill alarm = WRITE>=100MB).
__global__ __launch_bounds__(512) void qkv_mfma(
    const float* __restrict__ inp, const unsigned short* __restrict__ wt_hi,
    const unsigned short* __restrict__ wt_lo, float* __restrict__ qf,
    unsigned short* __restrict__ khi, unsigned short* __restrict__ klo,
    unsigned short* __restrict__ vtb) {
  __shared__ unsigned short Bh0[192 * 72];
  __shared__ unsigned short Bl0[192 * 72];
  __shared__ unsigned short Bh1[192 * 72];
  __shared__ unsigned short Bl1[192 * 72];
  const int t = threadIdx.x, lane = t & 63, w = t >> 6;
  const int m = lane & 15, quad = lane >> 4;
  const int rg = w >> 2, cg = w & 3;   // 2 row-groups x 4 col-groups
  const int tok0 = blockIdx.x * 64;
  const int arow0 = tok0 + rg * 32 + m;        // row-frag 0
  const int arow1 = arow0 + 16;                // row-frag 1

  f32x4 acc[6];  // [rf*3 + nt]
#pragma unroll
  for (int nt = 0; nt < 6; ++nt) acc[nt] = (f32x4){0.f, 0.f, 0.f, 0.f};

  // staging: 192 rows x 64 K-shorts = 1536 uint4 slots per array.
  // thread t owns slots t, t+512, t+1024.  slot s: n3 = s>>3, k8 = s&7.
  const int s0 = t, s1 = t + 512, s2 = t + 1024;
  const int n3_0 = s0 >> 3, k8_0 = s0 & 7;
  const int n3_1 = s1 >> 3, k8_1 = s1 & 7;
  const int n3_2 = s2 >> 3, k8_2 = s2 & 7;
  const size_t goff0 = (size_t)n3_0 * EMB + k8_0 * 8;
  const size_t goff1 = (size_t)n3_1 * EMB + k8_1 * 8;
  const size_t goff2 = (size_t)n3_2 * EMB + k8_2 * 8;
  const int lds0 = n3_0 * 72 + k8_0 * 8;
  const int lds1 = n3_1 * 72 + k8_1 * 8;
  const int lds2 = n3_2 * 72 + k8_2 * 8;

#define LOAD_B(K0, PH0, PH1, PH2, PL0, PL1, PL2)            \
  PH0 = *(const uint4*)&wt_hi[goff0 + (K0)];                \
  PH1 = *(const uint4*)&wt_hi[goff1 + (K0)];                \
  PH2 = *(const uint4*)&wt_hi[goff2 + (K0)];                \
  PL0 = *(const uint4*)&wt_lo[goff0 + (K0)];                \
  PL1 = *(const uint4*)&wt_lo[goff1 + (K0)];                \
  PL2 = *(const uint4*)&wt_lo[goff2 + (K0)];

#define STORE_B(BH, BL, PH0, PH1, PH2, PL0, PL1, PL2)       \
  *(uint4*)&BH[lds0] = PH0;                                 \
  *(uint4*)&BH[lds1] = PH1;                                 \
  *(uint4*)&BH[lds2] = PH2;                                 \
  *(uint4*)&BL[lds0] = PL0;                                 \
  *(uint4*)&BL[lds1] = PL1;                                 \
  *(uint4*)&BL[lds2] = PL2;

#define LOAD_A2(K0, P0, P1, P2, P3, P4, P5, P6, P7)                  \
  {                                                                  \
    const float* ap0 = &inp[(size_t)arow0 * EMB + (K0) + quad * 8];  \
    P0 = *(const float4*)ap0;        P1 = *(const float4*)(ap0 + 4); \
    P2 = *(const float4*)(ap0 + 32); P3 = *(const float4*)(ap0 + 36);\
    const float* ap1 = &inp[(size_t)arow1 * EMB + (K0) + quad * 8];  \
    P4 = *(const float4*)ap1;        P5 = *(const float4*)(ap1 + 4); \
    P6 = *(const float4*)(ap1 + 32); P7 = *(const float4*)(ap1 + 36);\
  }

// 36 MFMA, 12 B-reads: b-fragments shared by both row-frags in-register.
#define QKV_TILE(BH, BL, AH00, AL00, AH01, AL01, AH10, AL10, AH11, AL11)     \
  {                                                                          \
    _Pragma("unroll")                                                        \
    for (int nt = 0; nt < 3; ++nt) {                                         \
      const int bbase = (cg * 48 + nt * 16 + m) * 72;                        \
      s16x8 bh0 = *(const s16x8*)&BH[bbase + quad * 8];                      \
      s16x8 bl0 = *(const s16x8*)&BL[bbase + quad * 8];                      \
      s16x8 bh1 = *(const s16x8*)&BH[bbase + 32 + quad * 8];                 \
      s16x8 bl1 = *(const s16x8*)&BL[bbase + 32 + quad * 8];                 \
      f32x4 a0 = acc[nt];                                                    \
      a0 = __builtin_amdgcn_mfma_f32_16x16x32_bf16(AH00, bh0, a0, 0, 0, 0);  \
      a0 = __builtin_amdgcn_mfma_f32_16x16x32_bf16(AH00, bl0, a0, 0, 0, 0);  \
      a0 = __builtin_amdgcn_mfma_f32_16x16x32_bf16(AL00, bh0, a0, 0, 0, 0);  \
      a0 = __builtin_amdgcn_mfma_f32_16x16x32_bf16(AH01, bh1, a0, 0, 0, 0);  \
      a0 = __builtin_amdgcn_mfma_f32_16x16x32_bf16(AH01, bl1, a0, 0, 0, 0);  \
      a0 = __builtin_amdgcn_mfma_f32_16x16x32_bf16(AL01, bh1, a0, 0, 0, 0);  \
      acc[nt] = a0;                                                          \
      f32x4 a1 = acc[3 + nt];                                                \
      a1 = __builtin_amdgcn_mfma_f32_16x16x32_bf16(AH10, bh0, a1, 0, 0, 0);  \
      a1 = __builtin_amdgcn_mfma_f32_16x16x32_bf16(AH10, bl0, a1, 0, 0, 0);  \
      a1 = __builtin_amdgcn_mfma_f32_16x16x32_bf16(AL10, bh0, a1, 0, 0, 0);  \
      a1 = __builtin_amdgcn_mfma_f32_16x16x32_bf16(AH11, bh1, a1, 0, 0, 0);  \
      a1 = __builtin_amdgcn_mfma_f32_16x16x32_bf16(AH11, bl1, a1, 0, 0, 0);  \
      a1 = __builtin_amdgcn_mfma_f32_16x16x32_bf16(AL11, bh1, a1, 0, 0, 0);  \
      acc[3 + nt] = a1;                                                      \
    }                                                                        \
  }

  // two named register sets (even/odd sub-iter) — rule #20, no arrays
  uint4 phA0, phA1, phA2, plA0, plA1, plA2;
  uint4 phB0, phB1, phB2, plB0, plB1, plB2;
  float4 paA0, paA1, paA2, paA3, paA4, paA5, paA6, paA7;
  float4 paB0, paB1, paB2, paB3, paB4, paB5, paB6, paB7;

  // preamble: buf0 <- B(0); odd-set <- B(1), A(1); even-set A <- A(0)
  LOAD_B(0, phA0, phA1, phA2, plA0, plA1, plA2);
  LOAD_A2(0, paA0, paA1, paA2, paA3, paA4, paA5, paA6, paA7);
  STORE_B(Bh0, Bl0, phA0, phA1, phA2, plA0, plA1, plA2);
  LOAD_B(64, phB0, phB1, phB2, plB0, plB1, plB2);
  LOAD_A2(64, paB0, paB1, paB2, paB3, paB4, paB5, paB6, paB7);
  __syncthreads();

#pragma unroll 1
  for (int kc = 0; kc < 8; ++kc) {
    const int kbase = kc * 128;
    // ---- EVEN sub-iter: tile 2kc from buf0; odd-set holds B(2kc+1) ----
    STORE_B(Bh1, Bl1, phB0, phB1, phB2, plB0, plB1, plB2);  // buf1 <- B(2kc+1)
    if (kc < 7) { LOAD_B(kbase + 128, phA0, phA1, phA2, plA0, plA1, plA2); }
    {
      s16x8 ah00, al00, ah01, al01, ah10, al10, ah11, al11;
      cvt8t(paA0, paA1, ah00, al00);
      cvt8t(paA2, paA3, ah01, al01);
      cvt8t(paA4, paA5, ah10, al10);
      cvt8t(paA6, paA7, ah11, al11);
      if (kc < 7) { LOAD_A2(kbase + 128, paA0, paA1, paA2, paA3, paA4, paA5, paA6, paA7); }
      QKV_TILE(Bh0, Bl0, ah00, al00, ah01, al01, ah10, al10, ah11, al11);
    }
    __syncthreads();
    // ---- ODD sub-iter: tile 2kc+1 from buf1; even-set holds B(2kc+2) ----
    if (kc < 7) { STORE_B(Bh0, Bl0, phA0, phA1, phA2, plA0, plA1, plA2); }
    {
      s16x8 ah00, al00, ah01, al01, ah10, al10, ah11, al11;
      cvt8t(paB0, paB1, ah00, al00);
      cvt8t(paB2, paB3, ah01, al01);
      cvt8t(paB4, paB5, ah10, al10);
      cvt8t(paB6, paB7, ah11, al11);
      if (kc < 7) {
        LOAD_B(kbase + 192, phB0, phB1, phB2, plB0, plB1, plB2);
        LOAD_A2(kbase + 192, paB0, paB1, paB2, paB3, paB4, paB5, paB6, paB7);
      }
      QKV_TILE(Bh1, Bl1, ah00, al00, ah01, al01, ah10, al10, ah11, al11);
    }
    if (kc < 7) __syncthreads();
  }

#undef LOAD_B
#undef STORE_B
#undef LOAD_A2
#undef QKV_TILE

  // epilogue: C row = rg*32 + rf*16 + quad*4+r (token), col = m
#pragma unroll
  for (int rf = 0; rf < 2; ++rf) {
#pragma unroll
    for (int nt = 0; nt < 3; ++nt) {
      int n3 = cg * 48 + nt * 16 + m;
      int which = n3 >> 6, col = n3 & 63;
#pragma unroll
      for (int r = 0; r < 4; ++r) {
        int tok = tok0 + rg * 32 + rf * 16 + quad * 4 + r;
        float val = acc[rf * 3 + nt][r];
        if (which == 0) {
          qf[(size_t)tok * HS + col] = val;
        } else if (which == 1) {
          unsigned short h = f2bf(val);
          khi[(size_t)tok * HS + col] = h;
          klo[(size_t)tok * HS + col] = f2bf(val - bf2f(h));
        } else {
          vtb[(size_t)(tok >> 6) * 4096 + (size_t)col * 64 + (tok & 63)] = f2bf(val);
        }
      }
    }
  }
}

// ---------------- Kernel 2a: flash partials (verbatim — best measured) ----
__global__ __launch_bounds__(256) void attn_part(
    const float* __restrict__ q, const unsigned short* __restrict__ khi,
    const unsigned short* __restrict__ klo, const unsigned short* __restrict__ vt,
    unsigned short* __restrict__ partO, float* __restrict__ partML) {
  __shared__ unsigned short Khi_s[64 * 72];
  __shared__ unsigned short Klo_s[64 * 72];
  __shared__ unsigned short Vt_s[64 * 72];
  __shared__ unsigned short P_s[4 * 16 * 72];
  const int t = threadIdx.x;
  const int lane = t & 63, w = t >> 6;
  const int m = lane & 15, quad = lane >> 4;

  int u = blockIdx.x;
  const int b = u / 160;
  u -= b * 160;
  int qtile = 0, c = 0;
  {
    int acc2 = 0;
    for (int qq = 0; qq < 64; ++qq) {
      int ncq = (qq >> 4) + 1;
      if (u < acc2 + ncq) { qtile = qq; c = u - acc2; break; }
      acc2 += ncq;
    }
  }
  const int kt0 = c * 16;
  const int kt1 = (kt0 + 16 < qtile + 1) ? kt0 + 16 : qtile + 1;

  const size_t qrow0 = (size_t)b * T_SEQ + (size_t)qtile * 64;
  const size_t krowbase = (size_t)b * T_SEQ;
  const int q_loc = w * 16 + m;

  s16x8 qh[2], ql[2];
#pragma unroll
  for (int cc = 0; cc < 2; ++cc) {
    const float* qp = &q[(qrow0 + q_loc) * HS + cc * 32 + quad * 8];
    cvt8(*(const float4*)qp, *(const float4*)(qp + 4), qh[cc], ql[cc]);
  }

  float l_st = 0.f;
  f32x4 o[4];
#pragma unroll
  for (int hb = 0; hb < 4; ++hb) o[hb] = (f32x4){0.f, 0.f, 0.f, 0.f};

  const int r0 = t >> 3, ch0 = t & 7;
  const int r1 = (256 + t) >> 3, ch1 = t & 7;

  uint4 pk0h, pk0l, pv0, pk1h, pk1l, pv1;
  {
    size_t g0 = (krowbase + (size_t)kt0 * 64 + r0) * HS + ch0 * 8;
    size_t g1 = (krowbase + (size_t)kt0 * 64 + r1) * HS + ch1 * 8;
    pk0h = *(const uint4*)&khi[g0]; pk0l = *(const uint4*)&klo[g0];
    pk1h = *(const uint4*)&khi[g1]; pk1l = *(const uint4*)&klo[g1];
    size_t v0 = (size_t)(b * 64 + kt0) * 4096 + (size_t)r0 * 64 + ch0 * 8;
    size_t v1 = (size_t)(b * 64 + kt0) * 4096 + (size_t)r1 * 64 + ch1 * 8;
    pv0 = *(const uint4*)&vt[v0]; pv1 = *(const uint4*)&vt[v1];
  }

  for (int kt = kt0; kt < kt1; ++kt) {
    __syncthreads();
    *(uint4*)&Khi_s[r0 * 72 + ch0 * 8] = pk0h;
    *(uint4*)&Klo_s[r0 * 72 + ch0 * 8] = pk0l;
    *(uint4*)&Vt_s[r0 * 72 + ch0 * 8] = pv0;
    *(uint4*)&Khi_s[r1 * 72 + ch1 * 8] = pk1h;
    *(uint4*)&Klo_s[r1 * 72 + ch1 * 8] = pk1l;
    *(uint4*)&Vt_s[r1 * 72 + ch1 * 8] = pv1;
    __syncthreads();

    if (kt + 1 < kt1) {
      size_t g0 = (krowbase + (size_t)(kt + 1) * 64 + r0) * HS + ch0 * 8;
      size_t g1 = (krowbase + (size_t)(kt + 1) * 64 + r1) * HS + ch1 * 8;
      pk0h = *(const uint4*)&khi[g0]; pk0l = *(const uint4*)&klo[g0];
      pk1h = *(const uint4*)&khi[g1]; pk1l = *(const uint4*)&klo[g1];
      size_t v0 = (size_t)(b * 64 + kt + 1) * 4096 + (size_t)r0 * 64 + ch0 * 8;
      size_t v1 = (size_t)(b * 64 + kt + 1) * 4096 + (size_t)r1 * 64 + ch1 * 8;
      pv0 = *(const uint4*)&vt[v0]; pv1 = *(const uint4*)&vt[v1];
    }

    f32x4 st[4];
#pragma unroll
    for (int cb = 0; cb < 4; ++cb) {
      st[cb] = (f32x4){0.f, 0.f, 0.f, 0.f};
#pragma unroll
      for (int cc = 0; cc < 2; ++cc) {
        s16x8 bh = *(const s16x8*)&Khi_s[(cb * 16 + m) * 72 + cc * 32 + quad * 8];
        s16x8 bl = *(const s16x8*)&Klo_s[(cb * 16 + m) * 72 + cc * 32 + quad * 8];
        st[cb] = __builtin_amdgcn_mfma_f32_16x16x32_bf16(bh, qh[cc], st[cb], 0, 0, 0);
        st[cb] = __builtin_amdgcn_mfma_f32_16x16x32_bf16(bl, qh[cc], st[cb], 0, 0, 0);
        st[cb] = __builtin_amdgcn_mfma_f32_16x16x32_bf16(bh, ql[cc], st[cb], 0, 0, 0);
      }
    }
    if (kt == qtile) {
#pragma unroll
      for (int cb = 0; cb < 4; ++cb)
#pragma unroll
        for (int r = 0; r < 4; ++r)
          if (cb * 16 + quad * 4 + r > q_loc) st[cb][r] = -1e30f;
    }
#pragma unroll
    for (int cb = 0; cb < 4; ++cb)
#pragma unroll
      for (int r = 0; r < 4; ++r) {
        st[cb][r] = __expf(st[cb][r]);
        l_st += st[cb][r];
      }
#pragma unroll
    for (int cb = 0; cb < 4; ++cb) {
      uint2 pk;
      pk.x = (unsigned)f2bf(st[cb][0]) | ((unsigned)f2bf(st[cb][1]) << 16);
      pk.y = (unsigned)f2bf(st[cb][2]) | ((unsigned)f2bf(st[cb][3]) << 16);
      *(uint2*)&P_s[q_loc * 72 + cb * 16 + quad * 4] = pk;
    }
    s16x8 pf[2];
#pragma unroll
    for (int cc = 0; cc < 2; ++cc)
      pf[cc] = *(const s16x8*)&P_s[q_loc * 72 + cc * 32 + quad * 8];
#pragma unroll
    for (int hb = 0; hb < 4; ++hb) {
#pragma unroll
      for (int cc = 0; cc < 2; ++cc) {
        s16x8 vf = *(const s16x8*)&Vt_s[(hb * 16 + m) * 72 + cc * 32 + quad * 8];
        o[hb] = __builtin_amdgcn_mfma_f32_16x16x32_bf16(vf, pf[cc], o[hb], 0, 0, 0);
      }
    }
  }

  l_st += __shfl_xor(l_st, 16, 64);
  l_st += __shfl_xor(l_st, 32, 64);

  const int slot = ((b * 64 + qtile) << 2) + c;
  unsigned short* Op = partO + (size_t)slot * 4096;
#pragma unroll
  for (int hb = 0; hb < 4; ++hb) {
    uint2 pk;
    pk.x = (unsigned)f2bf(o[hb][0]) | ((unsigned)f2bf(o[hb][1]) << 16);
    pk.y = (unsigned)f2bf(o[hb][2]) | ((unsigned)f2bf(o[hb][3]) << 16);
    *(uint2*)&Op[q_loc * 64 + hb * 16 + quad * 4] = pk;
  }
  if (quad == 0) partML[(size_t)slot * 64 + q_loc] = l_st;
}

// ---------------- Kernel 2b: combine = plain sums (flat softmax) ----------
__global__ __launch_bounds__(256) void attn_combine(
    const unsigned short* __restrict__ partO, const float* __restrict__ partML,
    float* __restrict__ out) {
  const int qtile = blockIdx.x, b = blockIdx.y;
  const int t = threadIdx.x;
  const int row = t >> 2, hg = t & 3;
  const int nc = (qtile >> 4) + 1;
  const int slot0 = (b * 64 + qtile) << 2;

  float lsum = 0.f;
  for (int i = 0; i < nc; ++i) lsum += partML[(size_t)(slot0 + i) * 64 + row];
  const float inv = 1.f / (lsum * 8.0f);  // ref divides by sqrt(64) after softmax

  float acc[16];
#pragma unroll
  for (int e = 0; e < 16; ++e) acc[e] = 0.f;
  for (int i = 0; i < nc; ++i) {
    const unsigned short* Op =
        partO + (size_t)(slot0 + i) * 4096 + row * 64 + hg * 16;
    uint4 u0 = *(const uint4*)Op;
    uint4 u1 = *(const uint4*)(Op + 8);
    unsigned uv[8] = {u0.x, u0.y, u0.z, u0.w, u1.x, u1.y, u1.z, u1.w};
#pragma unroll
    for (int e = 0; e < 8; ++e) {
      acc[2 * e] += bf2f((unsigned short)(uv[e] & 0xFFFF));
      acc[2 * e + 1] += bf2f((unsigned short)(uv[e] >> 16));
    }
  }
  float* op = &out[((size_t)b * T_SEQ + (size_t)qtile * 64 + row) * HS + hg * 16];
#pragma unroll
  for (int v = 0; v < 4; ++v) {
    float4 r;
    r.x = acc[4 * v + 0] * inv; r.y = acc[4 * v + 1] * inv;
    r.z = acc[4 * v + 2] * inv; r.w = acc[4 * v + 3] * inv;
    ((float4*)op)[v] = r;
  }
}

extern "C" void kernel_launch(void* const* d_in, const int* in_sizes, int n_in,
                              void* d_out, int out_size, void* d_ws, size_t ws_size,
                              hipStream_t stream) {
  const float* inp = (const float*)d_in[0];
  const float* Wq  = (const float*)d_in[1];
  const float* Wk  = (const float*)d_in[2];
  const float* Wv  = (const float*)d_in[3];
  float* out = (float*)d_out;

  // ws: qf 4MB | khi 2MB | klo 2MB | vt 2MB | wt_hi .375MB | wt_lo .375MB
  //     | partO bf16 8MB | partML 256KB  (~19 MB)
  char* base = (char*)d_ws;
  float* qf = (float*)base;
  unsigned short* khi = (unsigned short*)(base + (size_t)BT * HS * 4);
  unsigned short* klo = khi + (size_t)BT * HS;
  unsigned short* vtb = klo + (size_t)BT * HS;
  unsigned short* wt_hi = vtb + (size_t)BT * HS;
  unsigned short* wt_lo = wt_hi + (size_t)192 * EMB;
  unsigned short* partO = wt_lo + (size_t)192 * EMB;
  float* partML = (float*)(partO + (size_t)1024 * 4096);

  wconv<<<dim3(192), dim3(256), 0, stream>>>(Wq, Wk, Wv, wt_hi, wt_lo);
  qkv_mfma<<<dim3(BT / 64), dim3(512), 0, stream>>>(inp, wt_hi, wt_lo, qf, khi, klo, vtb);
  attn_part<<<dim3(640), dim3(256), 0, stream>>>(qf, khi, klo, vtb, partO, partML);
  attn_combine<<<dim3(64, NBATCH), dim3(256), 0, stream>>>(partO, partML, out);
}

// Round 7
// 172.514 us; speedup vs baseline: 1.0712x; 1.0323x over previous
//
#include <hip/hip_runtime.h>

#define T_SEQ 4096
#define NBATCH 4
#define EMB 1024
#define HS 64
#define BT (NBATCH * T_SEQ)   // 16384 token rows

typedef float f32x4 __attribute__((ext_vector_type(4)));
typedef short s16x8 __attribute__((ext_vector_type(8)));

__device__ __forceinline__ unsigned short f2bf(float x) {  // RNE fp32->bf16
  union { float f; unsigned u; } c; c.f = x;
  unsigned r = c.u + 0x7FFF + ((c.u >> 16) & 1);
  return (unsigned short)(r >> 16);
}
__device__ __forceinline__ float bf2f(unsigned short h) {
  union { unsigned u; float f; } c; c.u = ((unsigned)h) << 16;
  return c.f;
}
// RNE hi/lo split (cold paths: wconv, epilogues, attn Q)
__device__ __forceinline__ void cvt8(float4 a0, float4 a1, s16x8& hi, s16x8& lo) {
  float xv[8] = {a0.x, a0.y, a0.z, a0.w, a1.x, a1.y, a1.z, a1.w};
#pragma unroll
  for (int j = 0; j < 8; ++j) {
    unsigned short h = f2bf(xv[j]);
    hi[j] = (short)h;
    lo[j] = (short)f2bf(xv[j] - bf2f(h));
  }
}
// TRUNCATION hi/lo split for the qkv hot loop (R4-proven).
__device__ __forceinline__ void cvt8t(float4 a0, float4 a1, s16x8& hi, s16x8& lo) {
  float xv[8] = {a0.x, a0.y, a0.z, a0.w, a1.x, a1.y, a1.z, a1.w};
  unsigned hu[8], lu[8];
#pragma unroll
  for (int j = 0; j < 8; ++j) {
    union { float f; unsigned u; } c; c.f = xv[j];
    hu[j] = c.u;
    union { unsigned u; float f; } hf; hf.u = c.u & 0xFFFF0000u;
    union { float f; unsigned u; } r; r.f = xv[j] - hf.f;
    lu[j] = r.u;
  }
  union { s16x8 v; unsigned u[4]; } H, L;
#pragma unroll
  for (int j = 0; j < 4; ++j) {
    H.u[j] = (hu[2 * j] >> 16) | (hu[2 * j + 1] & 0xFFFF0000u);
    L.u[j] = (lu[2 * j] >> 16) | (lu[2 * j + 1] & 0xFFFF0000u);
  }
  hi = H.v; lo = L.v;
}

// global -> LDS direct DMA, 16B per lane (wave writes base + lane*16).
__device__ __forceinline__ void gl16(const void* g, void* l) {
  __builtin_amdgcn_global_load_lds(
      (const __attribute__((address_space(1))) void*)g,
      (__attribute__((address_space(3))) void*)l, 16, 0, 0);
}

// ---------------- Kernel 0: W -> W^T hi/lo bf16 (verbatim) ---------------
__global__ __launch_bounds__(256) void wconv(
    const float* __restrict__ Wq, const float* __restrict__ Wk,
    const float* __restrict__ Wv, unsigned short* __restrict__ wt_hi,
    unsigned short* __restrict__ wt_lo) {
  const int n3 = blockIdx.x;
  const int which = n3 >> 6, n = n3 & 63;
  const float* W = (which == 0) ? Wq : (which == 1) ? Wk : Wv;
#pragma unroll
  for (int i = 0; i < 4; ++i) {
    int k = i * 256 + threadIdx.x;
    float x = W[(size_t)k * HS + n];
    unsigned short h = f2bf(x);
    wt_hi[(size_t)n3 * EMB + k] = h;
    wt_lo[(size_t)n3 * EMB + k] = f2bf(x - bf2f(h));
  }
}

// ---------------- Kernel 1: QKV projection v8 ----------------------------
// R4 geometry (best: 45us): 64tok x 192col, K-chunk 64, dbuf LDS, one
// barrier/subtile, 8 waves = 4rg x 2cg, 36 MFMA/wave/subtile, cvt8t.
// NEW: B staging via global_load_lds width=16 (no VGPR round-trip, no
// ds_write, ~48 fewer regs). Issued at PHASE TOP -> full compute phase of
// latency cover before the barrier's vmcnt(0) drain.
// gload_lds writes linearly (m104), so LDS is unpadded [192][64] with
// rule-#21 both-sides swizzle: source col16' = (l&7)^(l>>3), read
// col16 ^ (m&7) — same involution; ~8-way b128 spread (= padded layout).
// Buf layout (shorts): hi = [0,12288), lo = [12288,24576); 48KB/buf.
__global__ __launch_bounds__(512) void qkv_mfma(
    const float* __restrict__ inp, const unsigned short* __restrict__ wt_hi,
    const unsigned short* __restrict__ wt_lo, float* __restrict__ qf,
    unsigned short* __restrict__ khi, unsigned short* __restrict__ klo,
    unsigned short* __restrict__ vtb) {
  __shared__ __align__(16) unsigned short S0[24576];
  __shared__ __align__(16) unsigned short S1[24576];
  const int t = threadIdx.x, lane = t & 63, w = t >> 6;
  const int m = lane & 15, quad = lane >> 4;
  const int mg = w >> 1, ng = w & 1;   // 4 row-groups x 2 col-groups
  const int tok0 = blockIdx.x * 64;
  const int arow = tok0 + mg * 16 + m;

  f32x4 acc[6];
#pragma unroll
  for (int nt = 0; nt < 6; ++nt) acc[nt] = (f32x4){0.f, 0.f, 0.f, 0.f};

  // ---- staging invariants: wave w owns chunks {w, w+8, w+16} of hi and
  // {w+24, w+32, w+40} of lo; chunk c = 8 rows x 64 shorts = 1024B at
  // LDS short-offset c*512. Lane l: row-in-chunk rl = l>>3, swizzled
  // source col (shorts) cl = ((l&7)^rl)*8.
  const int rl = lane >> 3;
  const int cl = ((lane & 7) ^ rl) * 8;
  const unsigned short* ghi = wt_hi + (size_t)(w * 8 + rl) * EMB + cl;
  const unsigned short* glo = wt_lo + (size_t)(w * 8 + rl) * EMB + cl;
  unsigned short* const l0 = S0 + w * 512;
  unsigned short* const l1 = S1 + w * 512;

#define STAGE(LB, K0)                                    \
  gl16(ghi + (K0), (LB));                                \
  gl16(ghi + 64 * EMB + (K0), (LB) + 4096);              \
  gl16(ghi + 128 * EMB + (K0), (LB) + 8192);             \
  gl16(glo + (K0), (LB) + 12288);                        \
  gl16(glo + 64 * EMB + (K0), (LB) + 16384);             \
  gl16(glo + 128 * EMB + (K0), (LB) + 20480);

#define LOAD_A(K0, PA0, PA1, PA2, PA3)                               \
  {                                                                  \
    const float* ap = &inp[(size_t)arow * EMB + (K0) + quad * 8];    \
    PA0 = *(const float4*)ap;        PA1 = *(const float4*)(ap + 4); \
    PA2 = *(const float4*)(ap + 32); PA3 = *(const float4*)(ap + 36);\
  }

  // read-side swizzle constants (per-thread, loop-invariant)
  const int csw0 = (quad ^ (m & 7)) * 8;        // cc = 0 (K-shorts 0..31)
  const int csw1 = ((quad + 4) ^ (m & 7)) * 8;  // cc = 1 (K-shorts 32..63)

#define QKV_TILE(S, AH0, AL0, AH1, AL1)                                      \
  {                                                                          \
    _Pragma("unroll")                                                        \
    for (int nt = 0; nt < 6; ++nt) {                                         \
      const int bb = (ng * 96 + nt * 16 + m) * 64;                           \
      f32x4 a = acc[nt];                                                     \
      {                                                                      \
        s16x8 bh = *(const s16x8*)&S[bb + csw0];                             \
        s16x8 bl = *(const s16x8*)&S[12288 + bb + csw0];                     \
        a = __builtin_amdgcn_mfma_f32_16x16x32_bf16(AH0, bh, a, 0, 0, 0);    \
        a = __builtin_amdgcn_mfma_f32_16x16x32_bf16(AH0, bl, a, 0, 0, 0);    \
        a = __builtin_amdgcn_mfma_f32_16x16x32_bf16(AL0, bh, a, 0, 0, 0);    \
      }                                                                      \
      {                                                                      \
        s16x8 bh = *(const s16x8*)&S[bb + csw1];                             \
        s16x8 bl = *(const s16x8*)&S[12288 + bb + csw1];                     \
        a = __builtin_amdgcn_mfma_f32_16x16x32_bf16(AH1, bh, a, 0, 0, 0);    \
        a = __builtin_amdgcn_mfma_f32_16x16x32_bf16(AH1, bl, a, 0, 0, 0);    \
        a = __builtin_amdgcn_mfma_f32_16x16x32_bf16(AL1, bh, a, 0, 0, 0);    \
      }                                                                      \
      acc[nt] = a;                                                           \
    }                                                                        \
  }

  // two named A register sets (even/odd subtile) — rule #20, no arrays
  float4 paA0, paA1, paA2, paA3;
  float4 paB0, paB1, paB2, paB3;

  // prologue: S0 <- B(0); A(0) -> even set; A(1) -> odd set
  STAGE(l0, 0);
  LOAD_A(0, paA0, paA1, paA2, paA3);
  LOAD_A(64, paB0, paB1, paB2, paB3);
  __syncthreads();  // vmcnt(0) drain: S0 ready, A regs ready

#pragma unroll 1
  for (int kc = 0; kc < 8; ++kc) {
    // ---- EVEN subtile 2kc from S0; stage S1 <- B(2kc+1) ----
    STAGE(l1, (2 * kc + 1) * 64);
    {
      s16x8 ah0, al0, ah1, al1;
      cvt8t(paA0, paA1, ah0, al0);
      cvt8t(paA2, paA3, ah1, al1);
      if (kc < 7) { LOAD_A((2 * kc + 2) * 64, paA0, paA1, paA2, paA3); }
      QKV_TILE(S0, ah0, al0, ah1, al1);
    }
    __syncthreads();  // drains STAGE(S1) + A loads
    // ---- ODD subtile 2kc+1 from S1; stage S0 <- B(2kc+2) ----
    if (kc < 7) { STAGE(l0, (2 * kc + 2) * 64); }
    {
      s16x8 ah0, al0, ah1, al1;
      cvt8t(paB0, paB1, ah0, al0);
      cvt8t(paB2, paB3, ah1, al1);
      if (kc < 7) { LOAD_A((2 * kc + 3) * 64, paB0, paB1, paB2, paB3); }
      QKV_TILE(S1, ah0, al0, ah1, al1);
    }
    if (kc < 7) __syncthreads();
  }

#undef STAGE
#undef LOAD_A
#undef QKV_TILE

  // epilogue: C row = quad*4+r (token), col = m
#pragma unroll
  for (int nt = 0; nt < 6; ++nt) {
    int n3 = ng * 96 + nt * 16 + m;
    int which = n3 >> 6, col = n3 & 63;
#pragma unroll
    for (int r = 0; r < 4; ++r) {
      int tok = tok0 + mg * 16 + quad * 4 + r;
      float val = acc[nt][r];
      if (which == 0) {
        qf[(size_t)tok * HS + col] = val;
      } else if (which == 1) {
        unsigned short h = f2bf(val);
        khi[(size_t)tok * HS + col] = h;
        klo[(size_t)tok * HS + col] = f2bf(val - bf2f(h));
      } else {
        vtb[(size_t)(tok >> 6) * 4096 + (size_t)col * 64 + (tok & 63)] = f2bf(val);
      }
    }
  }
}

// ---------------- Kernel 2a: flash partials (verbatim — best measured) ----
__global__ __launch_bounds__(256) void attn_part(
    const float* __restrict__ q, const unsigned short* __restrict__ khi,
    const unsigned short* __restrict__ klo, const unsigned short* __restrict__ vt,
    unsigned short* __restrict__ partO, float* __restrict__ partML) {
  __shared__ unsigned short Khi_s[64 * 72];
  __shared__ unsigned short Klo_s[64 * 72];
  __shared__ unsigned short Vt_s[64 * 72];
  __shared__ unsigned short P_s[4 * 16 * 72];
  const int t = threadIdx.x;
  const int lane = t & 63, w = t >> 6;
  const int m = lane & 15, quad = lane >> 4;

  int u = blockIdx.x;
  const int b = u / 160;
  u -= b * 160;
  int qtile = 0, c = 0;
  {
    int acc2 = 0;
    for (int qq = 0; qq < 64; ++qq) {
      int ncq = (qq >> 4) + 1;
      if (u < acc2 + ncq) { qtile = qq; c = u - acc2; break; }
      acc2 += ncq;
    }
  }
  const int kt0 = c * 16;
  const int kt1 = (kt0 + 16 < qtile + 1) ? kt0 + 16 : qtile + 1;

  const size_t qrow0 = (size_t)b * T_SEQ + (size_t)qtile * 64;
  const size_t krowbase = (size_t)b * T_SEQ;
  const int q_loc = w * 16 + m;

  s16x8 qh[2], ql[2];
#pragma unroll
  for (int cc = 0; cc < 2; ++cc) {
    const float* qp = &q[(qrow0 + q_loc) * HS + cc * 32 + quad * 8];
    cvt8(*(const float4*)qp, *(const float4*)(qp + 4), qh[cc], ql[cc]);
  }

  float l_st = 0.f;
  f32x4 o[4];
#pragma unroll
  for (int hb = 0; hb < 4; ++hb) o[hb] = (f32x4){0.f, 0.f, 0.f, 0.f};

  const int r0 = t >> 3, ch0 = t & 7;
  const int r1 = (256 + t) >> 3, ch1 = t & 7;

  uint4 pk0h, pk0l, pv0, pk1h, pk1l, pv1;
  {
    size_t g0 = (krowbase + (size_t)kt0 * 64 + r0) * HS + ch0 * 8;
    size_t g1 = (krowbase + (size_t)kt0 * 64 + r1) * HS + ch1 * 8;
    pk0h = *(const uint4*)&khi[g0]; pk0l = *(const uint4*)&klo[g0];
    pk1h = *(const uint4*)&khi[g1]; pk1l = *(const uint4*)&klo[g1];
    size_t v0 = (size_t)(b * 64 + kt0) * 4096 + (size_t)r0 * 64 + ch0 * 8;
    size_t v1 = (size_t)(b * 64 + kt0) * 4096 + (size_t)r1 * 64 + ch1 * 8;
    pv0 = *(const uint4*)&vt[v0]; pv1 = *(const uint4*)&vt[v1];
  }

  for (int kt = kt0; kt < kt1; ++kt) {
    __syncthreads();
    *(uint4*)&Khi_s[r0 * 72 + ch0 * 8] = pk0h;
    *(uint4*)&Klo_s[r0 * 72 + ch0 * 8] = pk0l;
    *(uint4*)&Vt_s[r0 * 72 + ch0 * 8] = pv0;
    *(uint4*)&Khi_s[r1 * 72 + ch1 * 8] = pk1h;
    *(uint4*)&Klo_s[r1 * 72 + ch1 * 8] = pk1l;
    *(uint4*)&Vt_s[r1 * 72 + ch1 * 8] = pv1;
    __syncthreads();

    if (kt + 1 < kt1) {
      size_t g0 = (krowbase + (size_t)(kt + 1) * 64 + r0) * HS + ch0 * 8;
      size_t g1 = (krowbase + (size_t)(kt + 1) * 64 + r1) * HS + ch1 * 8;
      pk0h = *(const uint4*)&khi[g0]; pk0l = *(const uint4*)&klo[g0];
      pk1h = *(const uint4*)&khi[g1]; pk1l = *(const uint4*)&klo[g1];
      size_t v0 = (size_t)(b * 64 + kt + 1) * 4096 + (size_t)r0 * 64 + ch0 * 8;
      size_t v1 = (size_t)(b * 64 + kt + 1) * 4096 + (size_t)r1 * 64 + ch1 * 8;
      pv0 = *(const uint4*)&vt[v0]; pv1 = *(const uint4*)&vt[v1];
    }

    f32x4 st[4];
#pragma unroll
    for (int cb = 0; cb < 4; ++cb) {
      st[cb] = (f32x4){0.f, 0.f, 0.f, 0.f};
#pragma unroll
      for (int cc = 0; cc < 2; ++cc) {
        s16x8 bh = *(const s16x8*)&Khi_s[(cb * 16 + m) * 72 + cc * 32 + quad * 8];
        s16x8 bl = *(const s16x8*)&Klo_s[(cb * 16 + m) * 72 + cc * 32 + quad * 8];
        st[cb] = __builtin_amdgcn_mfma_f32_16x16x32_bf16(bh, qh[cc], st[cb], 0, 0, 0);
        st[cb] = __builtin_amdgcn_mfma_f32_16x16x32_bf16(bl, qh[cc], st[cb], 0, 0, 0);
        st[cb] = __builtin_amdgcn_mfma_f32_16x16x32_bf16(bh, ql[cc], st[cb], 0, 0, 0);
      }
    }
    if (kt == qtile) {
#pragma unroll
      for (int cb = 0; cb < 4; ++cb)
#pragma unroll
        for (int r = 0; r < 4; ++r)
          if (cb * 16 + quad * 4 + r > q_loc) st[cb][r] = -1e30f;
    }
#pragma unroll
    for (int cb = 0; cb < 4; ++cb)
#pragma unroll
      for (int r = 0; r < 4; ++r) {
        st[cb][r] = __expf(st[cb][r]);
        l_st += st[cb][r];
      }
#pragma unroll
    for (int cb = 0; cb < 4; ++cb) {
      uint2 pk;
      pk.x = (unsigned)f2bf(st[cb][0]) | ((unsigned)f2bf(st[cb][1]) << 16);
      pk.y = (unsigned)f2bf(st[cb][2]) | ((unsigned)f2bf(st[cb][3]) << 16);
      *(uint2*)&P_s[q_loc * 72 + cb * 16 + quad * 4] = pk;
    }
    s16x8 pf[2];
#pragma unroll
    for (int cc = 0; cc < 2; ++cc)
      pf[cc] = *(const s16x8*)&P_s[q_loc * 72 + cc * 32 + quad * 8];
#pragma unroll
    for (int hb = 0; hb < 4; ++hb) {
#pragma unroll
      for (int cc = 0; cc < 2; ++cc) {
        s16x8 vf = *(const s16x8*)&Vt_s[(hb * 16 + m) * 72 + cc * 32 + quad * 8];
        o[hb] = __builtin_amdgcn_mfma_f32_16x16x32_bf16(vf, pf[cc], o[hb], 0, 0, 0);
      }
    }
  }

  l_st += __shfl_xor(l_st, 16, 64);
  l_st += __shfl_xor(l_st, 32, 64);

  const int slot = ((b * 64 + qtile) << 2) + c;
  unsigned short* Op = partO + (size_t)slot * 4096;
#pragma unroll
  for (int hb = 0; hb < 4; ++hb) {
    uint2 pk;
    pk.x = (unsigned)f2bf(o[hb][0]) | ((unsigned)f2bf(o[hb][1]) << 16);
    pk.y = (unsigned)f2bf(o[hb][2]) | ((unsigned)f2bf(o[hb][3]) << 16);
    *(uint2*)&Op[q_loc * 64 + hb * 16 + quad * 4] = pk;
  }
  if (quad == 0) partML[(size_t)slot * 64 + q_loc] = l_st;
}

// ---------------- Kernel 2b: combine = plain sums (flat softmax) ----------
__global__ __launch_bounds__(256) void attn_combine(
    const unsigned short* __restrict__ partO, const float* __restrict__ partML,
    float* __restrict__ out) {
  const int qtile = blockIdx.x, b = blockIdx.y;
  const int t = threadIdx.x;
  const int row = t >> 2, hg = t & 3;
  const int nc = (qtile >> 4) + 1;
  const int slot0 = (b * 64 + qtile) << 2;

  float lsum = 0.f;
  for (int i = 0; i < nc; ++i) lsum += partML[(size_t)(slot0 + i) * 64 + row];
  const float inv = 1.f / (lsum * 8.0f);  // ref divides by sqrt(64) after softmax

  float acc[16];
#pragma unroll
  for (int e = 0; e < 16; ++e) acc[e] = 0.f;
  for (int i = 0; i < nc; ++i) {
    const unsigned short* Op =
        partO + (size_t)(slot0 + i) * 4096 + row * 64 + hg * 16;
    uint4 u0 = *(const uint4*)Op;
    uint4 u1 = *(const uint4*)(Op + 8);
    unsigned uv[8] = {u0.x, u0.y, u0.z, u0.w, u1.x, u1.y, u1.z, u1.w};
#pragma unroll
    for (int e = 0; e < 8; ++e) {
      acc[2 * e] += bf2f((unsigned short)(uv[e] & 0xFFFF));
      acc[2 * e + 1] += bf2f((unsigned short)(uv[e] >> 16));
    }
  }
  float* op = &out[((size_t)b * T_SEQ + (size_t)qtile * 64 + row) * HS + hg * 16];
#pragma unroll
  for (int v = 0; v < 4; ++v) {
    float4 r;
    r.x = acc[4 * v + 0] * inv; r.y = acc[4 * v + 1] * inv;
    r.z = acc[4 * v + 2] * inv; r.w = acc[4 * v + 3] * inv;
    ((float4*)op)[v] = r;
  }
}

extern "C" void kernel_launch(void* const* d_in, const int* in_sizes, int n_in,
                              void* d_out, int out_size, void* d_ws, size_t ws_size,
                              hipStream_t stream) {
  const float* inp = (const float*)d_in[0];
  const float* Wq  = (const float*)d_in[1];
  const float* Wk  = (const float*)d_in[2];
  const float* Wv  = (const float*)d_in[3];
  float* out = (float*)d_out;

  // ws: qf 4MB | khi 2MB | klo 2MB | vt 2MB | wt_hi .375MB | wt_lo .375MB
  //     | partO bf16 8MB | partML 256KB  (~19 MB)
  char* base = (char*)d_ws;
  float* qf = (float*)base;
  unsigned short* khi = (unsigned short*)(base + (size_t)BT * HS * 4);
  unsigned short* klo = khi + (size_t)BT * HS;
  unsigned short* vtb = klo + (size_t)BT * HS;
  unsigned short* wt_hi = vtb + (size_t)BT * HS;
  unsigned short* wt_lo = wt_hi + (size_t)192 * EMB;
  unsigned short* partO = wt_lo + (size_t)192 * EMB;
  float* partML = (float*)(partO + (size_t)1024 * 4096);

  wconv<<<dim3(192), dim3(256), 0, stream>>>(Wq, Wk, Wv, wt_hi, wt_lo);
  qkv_mfma<<<dim3(BT / 64), dim3(512), 0, stream>>>(inp, wt_hi, wt_lo, qf, khi, klo, vtb);
  attn_part<<<dim3(640), dim3(256), 0, stream>>>(qf, khi, klo, vtb, partO, partML);
  attn_combine<<<dim3(64, NBATCH), dim3(256), 0, stream>>>(partO, partML, out);
}

// Round 9
// 165.735 us; speedup vs baseline: 1.1150x; 1.0409x over previous
//
#include <hip/hip_runtime.h>

#define T_SEQ 4096
#define NBATCH 4
#define EMB 1024
#define HS 64
#define BT (NBATCH * T_SEQ)   // 16384 token rows

typedef float f32x4 __attribute__((ext_vector_type(4)));
typedef short s16x8 __attribute__((ext_vector_type(8)));

__device__ __forceinline__ unsigned short f2bf(float x) {  // RNE fp32->bf16
  union { float f; unsigned u; } c; c.f = x;
  unsigned r = c.u + 0x7FFF + ((c.u >> 16) & 1);
  return (unsigned short)(r >> 16);
}
__device__ __forceinline__ float bf2f(unsigned short h) {
  union { unsigned u; float f; } c; c.u = ((unsigned)h) << 16;
  return c.f;
}
// RNE hi/lo split (cold paths: wconv, epilogues, attn Q)
__device__ __forceinline__ void cvt8(float4 a0, float4 a1, s16x8& hi, s16x8& lo) {
  float xv[8] = {a0.x, a0.y, a0.z, a0.w, a1.x, a1.y, a1.z, a1.w};
#pragma unroll
  for (int j = 0; j < 8; ++j) {
    unsigned short h = f2bf(xv[j]);
    hi[j] = (short)h;
    lo[j] = (short)f2bf(xv[j] - bf2f(h));
  }
}
// TRUNCATION hi/lo split for the qkv hot loop (R4-proven).
__device__ __forceinline__ void cvt8t(float4 a0, float4 a1, s16x8& hi, s16x8& lo) {
  float xv[8] = {a0.x, a0.y, a0.z, a0.w, a1.x, a1.y, a1.z, a1.w};
  unsigned hu[8], lu[8];
#pragma unroll
  for (int j = 0; j < 8; ++j) {
    union { float f; unsigned u; } c; c.f = xv[j];
    hu[j] = c.u;
    union { unsigned u; float f; } hf; hf.u = c.u & 0xFFFF0000u;
    union { float f; unsigned u; } r; r.f = xv[j] - hf.f;
    lu[j] = r.u;
  }
  union { s16x8 v; unsigned u[4]; } H, L;
#pragma unroll
  for (int j = 0; j < 4; ++j) {
    H.u[j] = (hu[2 * j] >> 16) | (hu[2 * j + 1] & 0xFFFF0000u);
    L.u[j] = (lu[2 * j] >> 16) | (lu[2 * j + 1] & 0xFFFF0000u);
  }
  hi = H.v; lo = L.v;
}

// global -> LDS direct DMA, 16B per lane (wave writes base + lane*16).
__device__ __forceinline__ void gl16(const void* g, void* l) {
  __builtin_amdgcn_global_load_lds(
      (const __attribute__((address_space(1))) void*)g,
      (__attribute__((address_space(3))) void*)l, 16, 0, 0);
}

// ---------------- Kernel 0: W -> W^T hi/lo bf16 (verbatim) ---------------
__global__ __launch_bounds__(256) void wconv(
    const float* __restrict__ Wq, const float* __restrict__ Wk,
    const float* __restrict__ Wv, unsigned short* __restrict__ wt_hi,
    unsigned short* __restrict__ wt_lo) {
  const int n3 = blockIdx.x;
  const int which = n3 >> 6, n = n3 & 63;
  const float* W = (which == 0) ? Wq : (which == 1) ? Wk : Wv;
#pragma unroll
  for (int i = 0; i < 4; ++i) {
    int k = i * 256 + threadIdx.x;
    float x = W[(size_t)k * HS + n];
    unsigned short h = f2bf(x);
    wt_hi[(size_t)n3 * EMB + k] = h;
    wt_lo[(size_t)n3 * EMB + k] = f2bf(x - bf2f(h));
  }
}

// ---------------- Kernel 1: QKV projection v10 ---------------------------
// = R8 (counted vmcnt + raw barrier) with the ORDER-PINNING FIX (rule #18):
// R8 raced because vmcnt(4) assumed [6 STAGE][4 LOAD_A] issue order and the
// scheduler interleaved them -> stages could be the newest in-flight ops ->
// barrier passed with LDS writes pending. sched_barrier(0) after STAGE and
// around the waitcnt pins: stages oldest, A-loads newest, count sound.
__global__ __launch_bounds__(512) void qkv_mfma(
    const float* __restrict__ inp, const unsigned short* __restrict__ wt_hi,
    const unsigned short* __restrict__ wt_lo, float* __restrict__ qf,
    unsigned short* __restrict__ khi, unsigned short* __restrict__ klo,
    unsigned short* __restrict__ vtb) {
  __shared__ __align__(16) unsigned short S0[24576];
  __shared__ __align__(16) unsigned short S1[24576];
  const int t = threadIdx.x, lane = t & 63, w = t >> 6;
  const int m = lane & 15, quad = lane >> 4;
  const int mg = w >> 1, ng = w & 1;   // 4 row-groups x 2 col-groups
  const int tok0 = blockIdx.x * 64;
  const int arow = tok0 + mg * 16 + m;

  f32x4 acc[6];
#pragma unroll
  for (int nt = 0; nt < 6; ++nt) acc[nt] = (f32x4){0.f, 0.f, 0.f, 0.f};

  // staging invariants (R7): wave w owns chunks {w,w+8,w+16} of hi and the
  // same of lo at +12288; chunk = 8 rows x 64 shorts; lane l: rl = l>>3,
  // swizzled source col cl = ((l&7)^rl)*8.
  const int rl = lane >> 3;
  const int cl = ((lane & 7) ^ rl) * 8;
  const unsigned short* ghi = wt_hi + (size_t)(w * 8 + rl) * EMB + cl;
  const unsigned short* glo = wt_lo + (size_t)(w * 8 + rl) * EMB + cl;
  unsigned short* const l0 = S0 + w * 512;
  unsigned short* const l1 = S1 + w * 512;

#define SB0() __builtin_amdgcn_sched_barrier(0)

#define STAGE(LB, K0)                                    \
  gl16(ghi + (K0), (LB));                                \
  gl16(ghi + 64 * EMB + (K0), (LB) + 4096);              \
  gl16(ghi + 128 * EMB + (K0), (LB) + 8192);             \
  gl16(glo + (K0), (LB) + 12288);                        \
  gl16(glo + 64 * EMB + (K0), (LB) + 16384);             \
  gl16(glo + 128 * EMB + (K0), (LB) + 20480);            \
  SB0();  /* pin: stages issue before everything after */

#define LOAD_A(K0, PA0, PA1, PA2, PA3)                               \
  {                                                                  \
    const float* ap = &inp[(size_t)arow * EMB + (K0) + quad * 8];    \
    PA0 = *(const float4*)ap;        PA1 = *(const float4*)(ap + 4); \
    PA2 = *(const float4*)(ap + 32); PA3 = *(const float4*)(ap + 36);\
  }

// counted-vmcnt barrier (T4), order-pinned both sides (rule #18).
#define VMBAR(N)                                                        \
  {                                                                     \
    SB0();                                                              \
    asm volatile("s_waitcnt vmcnt(" #N ") lgkmcnt(0)" ::: "memory");    \
    SB0();                                                              \
    __builtin_amdgcn_s_barrier();                                       \
  }

  // read-side swizzle constants (per-thread, loop-invariant)
  const int csw0 = (quad ^ (m & 7)) * 8;        // cc = 0 (K-shorts 0..31)
  const int csw1 = ((quad + 4) ^ (m & 7)) * 8;  // cc = 1 (K-shorts 32..63)

#define QKV_TILE(S, AH0, AL0, AH1, AL1)                                      \
  {                                                                          \
    _Pragma("unroll")                                                        \
    for (int nt = 0; nt < 6; ++nt) {                                         \
      const int bb = (ng * 96 + nt * 16 + m) * 64;                           \
      f32x4 a = acc[nt];                                                     \
      {                                                                      \
        s16x8 bh = *(const s16x8*)&S[bb + csw0];                             \
        s16x8 bl = *(const s16x8*)&S[12288 + bb + csw0];                     \
        a = __builtin_amdgcn_mfma_f32_16x16x32_bf16(AH0, bh, a, 0, 0, 0);    \
        a = __builtin_amdgcn_mfma_f32_16x16x32_bf16(AH0, bl, a, 0, 0, 0);    \
        a = __builtin_amdgcn_mfma_f32_16x16x32_bf16(AL0, bh, a, 0, 0, 0);    \
      }                                                                      \
      {                                                                      \
        s16x8 bh = *(const s16x8*)&S[bb + csw1];                             \
        s16x8 bl = *(const s16x8*)&S[12288 + bb + csw1];                     \
        a = __builtin_amdgcn_mfma_f32_16x16x32_bf16(AH1, bh, a, 0, 0, 0);    \
        a = __builtin_amdgcn_mfma_f32_16x16x32_bf16(AH1, bl, a, 0, 0, 0);    \
        a = __builtin_amdgcn_mfma_f32_16x16x32_bf16(AL1, bh, a, 0, 0, 0);    \
      }                                                                      \
      acc[nt] = a;                                                           \
    }                                                                        \
  }

  // two named A register sets (even/odd subtile) — rule #20, no arrays
  float4 paA0, paA1, paA2, paA3;
  float4 paB0, paB1, paB2, paB3;

  // prologue: S0 <- B(0) [6 ops, pinned first]; A(0)+A(1) [8 ops, newest]
  STAGE(l0, 0);
  LOAD_A(0, paA0, paA1, paA2, paA3);
  LOAD_A(64, paB0, paB1, paB2, paB3);
  VMBAR(8);  // stages drained; 8 A-loads stay in flight

#pragma unroll 1
  for (int kc = 0; kc < 8; ++kc) {
    // ---- EVEN subtile 2kc from S0; stage S1 <- B(2kc+1) ----
    STAGE(l1, (2 * kc + 1) * 64);
    {
      s16x8 ah0, al0, ah1, al1;
      cvt8t(paA0, paA1, ah0, al0);
      cvt8t(paA2, paA3, ah1, al1);
      if (kc < 7) { LOAD_A((2 * kc + 2) * 64, paA0, paA1, paA2, paA3); }
      QKV_TILE(S0, ah0, al0, ah1, al1);
    }
    if (kc < 7) { VMBAR(4); } else { VMBAR(0); }
    // ---- ODD subtile 2kc+1 from S1; stage S0 <- B(2kc+2) ----
    if (kc < 7) { STAGE(l0, (2 * kc + 2) * 64); }
    {
      s16x8 ah0, al0, ah1, al1;
      cvt8t(paB0, paB1, ah0, al0);
      cvt8t(paB2, paB3, ah1, al1);
      if (kc < 7) { LOAD_A((2 * kc + 3) * 64, paB0, paB1, paB2, paB3); }
      QKV_TILE(S1, ah0, al0, ah1, al1);
    }
    if (kc < 7) VMBAR(4);
  }

#undef STAGE
#undef LOAD_A
#undef QKV_TILE
#undef VMBAR
#undef SB0

  // epilogue: C row = quad*4+r (token), col = m
#pragma unroll
  for (int nt = 0; nt < 6; ++nt) {
    int n3 = ng * 96 + nt * 16 + m;
    int which = n3 >> 6, col = n3 & 63;
#pragma unroll
    for (int r = 0; r < 4; ++r) {
      int tok = tok0 + mg * 16 + quad * 4 + r;
      float val = acc[nt][r];
      if (which == 0) {
        qf[(size_t)tok * HS + col] = val;
      } else if (which == 1) {
        unsigned short h = f2bf(val);
        khi[(size_t)tok * HS + col] = h;
        klo[(size_t)tok * HS + col] = f2bf(val - bf2f(h));
      } else {
        vtb[(size_t)(tok >> 6) * 4096 + (size_t)col * 64 + (tok & 63)] = f2bf(val);
      }
    }
  }
}

// ---------------- Kernel 2a: flash partials (verbatim — best measured) ----
__global__ __launch_bounds__(256) void attn_part(
    const float* __restrict__ q, const unsigned short* __restrict__ khi,
    const unsigned short* __restrict__ klo, const unsigned short* __restrict__ vt,
    unsigned short* __restrict__ partO, float* __restrict__ partML) {
  __shared__ unsigned short Khi_s[64 * 72];
  __shared__ unsigned short Klo_s[64 * 72];
  __shared__ unsigned short Vt_s[64 * 72];
  __shared__ unsigned short P_s[4 * 16 * 72];
  const int t = threadIdx.x;
  const int lane = t & 63, w = t >> 6;
  const int m = lane & 15, quad = lane >> 4;

  int u = blockIdx.x;
  const int b = u / 160;
  u -= b * 160;
  int qtile = 0, c = 0;
  {
    int acc2 = 0;
    for (int qq = 0; qq < 64; ++qq) {
      int ncq = (qq >> 4) + 1;
      if (u < acc2 + ncq) { qtile = qq; c = u - acc2; break; }
      acc2 += ncq;
    }
  }
  const int kt0 = c * 16;
  const int kt1 = (kt0 + 16 < qtile + 1) ? kt0 + 16 : qtile + 1;

  const size_t qrow0 = (size_t)b * T_SEQ + (size_t)qtile * 64;
  const size_t krowbase = (size_t)b * T_SEQ;
  const int q_loc = w * 16 + m;

  s16x8 qh[2], ql[2];
#pragma unroll
  for (int cc = 0; cc < 2; ++cc) {
    const float* qp = &q[(qrow0 + q_loc) * HS + cc * 32 + quad * 8];
    cvt8(*(const float4*)qp, *(const float4*)(qp + 4), qh[cc], ql[cc]);
  }

  float l_st = 0.f;
  f32x4 o[4];
#pragma unroll
  for (int hb = 0; hb < 4; ++hb) o[hb] = (f32x4){0.f, 0.f, 0.f, 0.f};

  const int r0 = t >> 3, ch0 = t & 7;
  const int r1 = (256 + t) >> 3, ch1 = t & 7;

  uint4 pk0h, pk0l, pv0, pk1h, pk1l, pv1;
  {
    size_t g0 = (krowbase + (size_t)kt0 * 64 + r0) * HS + ch0 * 8;
    size_t g1 = (krowbase + (size_t)kt0 * 64 + r1) * HS + ch1 * 8;
    pk0h = *(const uint4*)&khi[g0]; pk0l = *(const uint4*)&klo[g0];
    pk1h = *(const uint4*)&khi[g1]; pk1l = *(const uint4*)&klo[g1];
    size_t v0 = (size_t)(b * 64 + kt0) * 4096 + (size_t)r0 * 64 + ch0 * 8;
    size_t v1 = (size_t)(b * 64 + kt0) * 4096 + (size_t)r1 * 64 + ch1 * 8;
    pv0 = *(const uint4*)&vt[v0]; pv1 = *(const uint4*)&vt[v1];
  }

  for (int kt = kt0; kt < kt1; ++kt) {
    __syncthreads();
    *(uint4*)&Khi_s[r0 * 72 + ch0 * 8] = pk0h;
    *(uint4*)&Klo_s[r0 * 72 + ch0 * 8] = pk0l;
    *(uint4*)&Vt_s[r0 * 72 + ch0 * 8] = pv0;
    *(uint4*)&Khi_s[r1 * 72 + ch1 * 8] = pk1h;
    *(uint4*)&Klo_s[r1 * 72 + ch1 * 8] = pk1l;
    *(uint4*)&Vt_s[r1 * 72 + ch1 * 8] = pv1;
    __syncthreads();

    if (kt + 1 < kt1) {
      size_t g0 = (krowbase + (size_t)(kt + 1) * 64 + r0) * HS + ch0 * 8;
      size_t g1 = (krowbase + (size_t)(kt + 1) * 64 + r1) * HS + ch1 * 8;
      pk0h = *(const uint4*)&khi[g0]; pk0l = *(const uint4*)&klo[g0];
      pk1h = *(const uint4*)&khi[g1]; pk1l = *(const uint4*)&klo[g1];
      size_t v0 = (size_t)(b * 64 + kt + 1) * 4096 + (size_t)r0 * 64 + ch0 * 8;
      size_t v1 = (size_t)(b * 64 + kt + 1) * 4096 + (size_t)r1 * 64 + ch1 * 8;
      pv0 = *(const uint4*)&vt[v0]; pv1 = *(const uint4*)&vt[v1];
    }

    f32x4 st[4];
#pragma unroll
    for (int cb = 0; cb < 4; ++cb) {
      st[cb] = (f32x4){0.f, 0.f, 0.f, 0.f};
#pragma unroll
      for (int cc = 0; cc < 2; ++cc) {
        s16x8 bh = *(const s16x8*)&Khi_s[(cb * 16 + m) * 72 + cc * 32 + quad * 8];
        s16x8 bl = *(const s16x8*)&Klo_s[(cb * 16 + m) * 72 + cc * 32 + quad * 8];
        st[cb] = __builtin_amdgcn_mfma_f32_16x16x32_bf16(bh, qh[cc], st[cb], 0, 0, 0);
        st[cb] = __builtin_amdgcn_mfma_f32_16x16x32_bf16(bl, qh[cc], st[cb], 0, 0, 0);
        st[cb] = __builtin_amdgcn_mfma_f32_16x16x32_bf16(bh, ql[cc], st[cb], 0, 0, 0);
      }
    }
    if (kt == qtile) {
#pragma unroll
      for (int cb = 0; cb < 4; ++cb)
#pragma unroll
        for (int r = 0; r < 4; ++r)
          if (cb * 16 + quad * 4 + r > q_loc) st[cb][r] = -1e30f;
    }
#pragma unroll
    for (int cb = 0; cb < 4; ++cb)
#pragma unroll
      for (int r = 0; r < 4; ++r) {
        st[cb][r] = __expf(st[cb][r]);
        l_st += st[cb][r];
      }
#pragma unroll
    for (int cb = 0; cb < 4; ++cb) {
      uint2 pk;
      pk.x = (unsigned)f2bf(st[cb][0]) | ((unsigned)f2bf(st[cb][1]) << 16);
      pk.y = (unsigned)f2bf(st[cb][2]) | ((unsigned)f2bf(st[cb][3]) << 16);
      *(uint2*)&P_s[q_loc * 72 + cb * 16 + quad * 4] = pk;
    }
    s16x8 pf[2];
#pragma unroll
    for (int cc = 0; cc < 2; ++cc)
      pf[cc] = *(const s16x8*)&P_s[q_loc * 72 + cc * 32 + quad * 8];
#pragma unroll
    for (int hb = 0; hb < 4; ++hb) {
#pragma unroll
      for (int cc = 0; cc < 2; ++cc) {
        s16x8 vf = *(const s16x8*)&Vt_s[(hb * 16 + m) * 72 + cc * 32 + quad * 8];
        o[hb] = __builtin_amdgcn_mfma_f32_16x16x32_bf16(vf, pf[cc], o[hb], 0, 0, 0);
      }
    }
  }

  l_st += __shfl_xor(l_st, 16, 64);
  l_st += __shfl_xor(l_st, 32, 64);

  const int slot = ((b * 64 + qtile) << 2) + c;
  unsigned short* Op = partO + (size_t)slot * 4096;
#pragma unroll
  for (int hb = 0; hb < 4; ++hb) {
    uint2 pk;
    pk.x = (unsigned)f2bf(o[hb][0]) | ((unsigned)f2bf(o[hb][1]) << 16);
    pk.y = (unsigned)f2bf(o[hb][2]) | ((unsigned)f2bf(o[hb][3]) << 16);
    *(uint2*)&Op[q_loc * 64 + hb * 16 + quad * 4] = pk;
  }
  if (quad == 0) partML[(size_t)slot * 64 + q_loc] = l_st;
}

// ---------------- Kernel 2b: combine = plain sums (flat softmax) ----------
__global__ __launch_bounds__(256) void attn_combine(
    const unsigned short* __restrict__ partO, const float* __restrict__ partML,
    float* __restrict__ out) {
  const int qtile = blockIdx.x, b = blockIdx.y;
  const int t = threadIdx.x;
  const int row = t >> 2, hg = t & 3;
  const int nc = (qtile >> 4) + 1;
  const int slot0 = (b * 64 + qtile) << 2;

  float lsum = 0.f;
  for (int i = 0; i < nc; ++i) lsum += partML[(size_t)(slot0 + i) * 64 + row];
  const float inv = 1.f / (lsum * 8.0f);  // ref divides by sqrt(64) after softmax

  float acc[16];
#pragma unroll
  for (int e = 0; e < 16; ++e) acc[e] = 0.f;
  for (int i = 0; i < nc; ++i) {
    const unsigned short* Op =
        partO + (size_t)(slot0 + i) * 4096 + row * 64 + hg * 16;
    uint4 u0 = *(const uint4*)Op;
    uint4 u1 = *(const uint4*)(Op + 8);
    unsigned uv[8] = {u0.x, u0.y, u0.z, u0.w, u1.x, u1.y, u1.z, u1.w};
#pragma unroll
    for (int e = 0; e < 8; ++e) {
      acc[2 * e] += bf2f((unsigned short)(uv[e] & 0xFFFF));
      acc[2 * e + 1] += bf2f((unsigned short)(uv[e] >> 16));
    }
  }
  float* op = &out[((size_t)b * T_SEQ + (size_t)qtile * 64 + row) * HS + hg * 16];
#pragma unroll
  for (int v = 0; v < 4; ++v) {
    float4 r;
    r.x = acc[4 * v + 0] * inv; r.y = acc[4 * v + 1] * inv;
    r.z = acc[4 * v + 2] * inv; r.w = acc[4 * v + 3] * inv;
    ((float4*)op)[v] = r;
  }
}

extern "C" void kernel_launch(void* const* d_in, const int* in_sizes, int n_in,
                              void* d_out, int out_size, void* d_ws, size_t ws_size,
                              hipStream_t stream) {
  const float* inp = (const float*)d_in[0];
  const float* Wq  = (const float*)d_in[1];
  const float* Wk  = (const float*)d_in[2];
  const float* Wv  = (const float*)d_in[3];
  float* out = (float*)d_out;

  // ws: qf 4MB | khi 2MB | klo 2MB | vt 2MB | wt_hi .375MB | wt_lo .375MB
  //     | partO bf16 8MB | partML 256KB  (~19 MB)
  char* base = (char*)d_ws;
  float* qf = (float*)base;
  unsigned short* khi = (unsigned short*)(base + (size_t)BT * HS * 4);
  unsigned short* klo = khi + (size_t)BT * HS;
  unsigned short* vtb = klo + (size_t)BT * HS;
  unsigned short* wt_hi = vtb + (size_t)BT * HS;
  unsigned short* wt_lo = wt_hi + (size_t)192 * EMB;
  unsigned short* partO = wt_lo + (size_t)192 * EMB;
  float* partML = (float*)(partO + (size_t)1024 * 4096);

  wconv<<<dim3(192), dim3(256), 0, stream>>>(Wq, Wk, Wv, wt_hi, wt_lo);
  qkv_mfma<<<dim3(BT / 64), dim3(512), 0, stream>>>(inp, wt_hi, wt_lo, qf, khi, klo, vtb);
  attn_part<<<dim3(640), dim3(256), 0, stream>>>(qf, khi, klo, vtb, partO, partML);
  attn_combine<<<dim3(64, NBATCH), dim3(256), 0, stream>>>(partO, partML, out);
}